// Round 14
// baseline (131.828 us; speedup 1.0000x reference)
//
#include <hip/hip_runtime.h>

// Problem constants (fixed by setup_inputs): bs=8, m=4096, T=32, E=65536
#define M      4096
#define TT     32
#define BS     8
#define EE     65536
#define NROWS  (BS * M)                   // 32768
#define SLOTS  64                         // hash slots per row (load ~27%)
#define NBLK   (NROWS / 16)               // compute grid = 2048 blocks (2 rows/group)

// Slot table lives at the END of d_ws: the harness's 0xAA poison fill (256 MB,
// ~41 us, unavoidable) writes it LAST, so those lines are L2-dirty-resident
// when build starts -> warm atomics WITHOUT the 8 MB memset dispatch (R12
// showed cold-line CAS costs +25 us; R13 showed memset warm = fast).
// Any initial slot value outside [1,4096] acts as "empty" (poison 0xAA, zero,
// or garbage) -> correctness never depends on ws initial state.
#define SLOT_BYTES ((size_t)NROWS * SLOTS * 4)        // 8 MB
#define PART_BYTES ((size_t)NBLK * 4)                 // 8 KB
#define WS_NEED    (SLOT_BYTES + PART_BYTES + 512)

// ---------------- Fast path ----------------

// One edge per thread (max TLP). Open-addressed per-row hash via
// read-classify-CAS: values in [1,4096] are occupied entries, anything else
// is claimable. Dedup is free (match -> no-op).
__global__ __launch_bounds__(256) void build_slots(const int* __restrict__ coo,
                                                   unsigned int* __restrict__ slots) {
    int idx = blockIdx.x * 256 + threadIdx.x;     // [0, BS*EE)
    int b = idx >> 16;
    int e = idx & (EE - 1);
    const int* base = coo + (size_t)b * 2 * EE;
    int src = base[e] & (M - 1);
    int tgt = base[EE + e] & (M - 1);
    unsigned int* row = slots + ((size_t)(b * M + src) << 6);
    unsigned int val = (unsigned int)tgt + 1u;    // in [1, 4096]
    int s = tgt & (SLOTS - 1);
    unsigned int cur = row[s];                    // plain read; CAS verifies
    #pragma unroll 1
    for (int probe = 0; probe < 4 * SLOTS; ++probe) {
        if (cur == val) return;                   // dup -> done
        if (cur - 1u < 4096u) {                   // occupied by another target
            s = (s + 1) & (SLOTS - 1);
            cur = row[s];
            continue;
        }
        unsigned int old = atomicCAS(&row[s], cur, val);
        if (old == cur) return;                   // claimed
        cur = old;                                // re-examine same slot
    }
}

// One 32-lane group per TWO adjacent rows (lane = t = column). Slot loads for
// both rows coalesce (512 B); 64 shfl-broadcast gathers per row. Valid slot
// iff (v-1) < 4096; sentinels/garbage map to a fixed row (L1-resident line).
__global__ __launch_bounds__(256) void compute_slots(const float* __restrict__ y,
                                                     const unsigned int* __restrict__ slots,
                                                     float* __restrict__ partials) {
    __shared__ float wsum[4];
    const int tid = threadIdx.x;
    const int t = tid & 31;                        // column t
    const int grp = tid >> 5;                      // 8 groups/block
    const int rowA = blockIdx.x * 16 + grp * 2;    // two adjacent rows
    const int b = rowA >> 12;                      // same batch for both (16-aligned)
    const int iA = rowA & (M - 1);
    const int iB = iA + 1;

    const float* yb = y + (size_t)b * M * TT;
    const unsigned int* rs = slots + ((size_t)rowA << 6);
    unsigned int a0 = rs[t];                       // 512 B contiguous per group
    unsigned int a1 = rs[t + 32];
    unsigned int b0 = rs[t + 64];
    unsigned int b1 = rs[t + 96];

    float accA = yb[iA * TT + t];                  // identity (eye) terms
    float accB = yb[iB * TT + t];
    float ynA = (t < 31) ? yb[iA * TT + t + 1] : 0.0f;
    float ynB = (t < 31) ? yb[iB * TT + t + 1] : 0.0f;

    #pragma unroll 8
    for (int k = 0; k < 32; ++k) {
        unsigned int ja0 = __shfl(a0, k, 32);      // broadcast slot k to group
        unsigned int ja1 = __shfl(a1, k, 32);
        unsigned int jb0 = __shfl(b0, k, 32);
        unsigned int jb1 = __shfl(b1, k, 32);
        float va0 = yb[(((int)ja0 - 1) & (M - 1)) * TT + t];
        float va1 = yb[(((int)ja1 - 1) & (M - 1)) * TT + t];
        float vb0 = yb[(((int)jb0 - 1) & (M - 1)) * TT + t];
        float vb1 = yb[(((int)jb1 - 1) & (M - 1)) * TT + t];
        accA += (ja0 - 1u < 4096u) ? va0 : 0.0f;   // valid iff v in [1,4096]
        accA += (ja1 - 1u < 4096u) ? va1 : 0.0f;
        accB += (jb0 - 1u < 4096u) ? vb0 : 0.0f;
        accB += (jb1 - 1u < 4096u) ? vb1 : 0.0f;
    }

    float v = 0.0f;
    if (t < 31) v = fmaxf(ynA - accA, 0.0f) + fmaxf(ynB - accB, 0.0f);
    #pragma unroll
    for (int off = 32; off; off >>= 1) v += __shfl_down(v, off, 64);

    if ((tid & 63) == 0) wsum[tid >> 6] = v;
    __syncthreads();
    if (tid == 0) partials[blockIdx.x] = wsum[0] + wsum[1] + wsum[2] + wsum[3];
}

// Single block sums the 2048 partials. No atomics anywhere.
__global__ __launch_bounds__(1024) void reduce_partials(const float* __restrict__ p,
                                                        float* __restrict__ out) {
    const int tid = threadIdx.x;
    float s = 0.0f;
    for (int k = tid; k < NBLK; k += 1024) s += p[k];
    #pragma unroll
    for (int off = 32; off; off >>= 1) s += __shfl_down(s, off, 64);
    __shared__ float ws[16];
    if ((tid & 63) == 0) ws[tid >> 6] = s;
    __syncthreads();
    if (tid == 0) {
        float tot = 0.0f;
        #pragma unroll
        for (int k = 0; k < 16; ++k) tot += ws[k];
        out[0] = tot;
    }
}

// ---------------- Fallback (R3): LDS bitmap, no scratch ----------------
#define WPR    128
#define ROWS   64
#define NCHUNK (M / ROWS)

__global__ __launch_bounds__(256) void nil_reg_lds(const float* __restrict__ y,
                                                   const int* __restrict__ coo,
                                                   float* __restrict__ out) {
    __shared__ unsigned int bm[ROWS * WPR];
    const int tid = threadIdx.x;
    const int b = blockIdx.x / NCHUNK;
    const int chunk = blockIdx.x % NCHUNK;
    const int row0 = chunk * ROWS;
    for (int i = tid; i < ROWS * WPR; i += 256) bm[i] = 0;
    __syncthreads();
    const int* base = coo + (size_t)b * 2 * EE;
    for (int e = tid; e < EE; e += 256) {
        int src = base[e] & (M - 1);
        int tgt = base[EE + e] & (M - 1);
        int r = src - row0;
        if ((unsigned)r < (unsigned)ROWS)
            atomicOr(&bm[r * WPR + (tgt >> 5)], 1u << (tgt & 31));
    }
    __syncthreads();
    const float* yb = y + (size_t)b * M * TT;
    const int t = tid & 31;
    const int grp = tid >> 5;
    float total = 0.0f;
    for (int r = grp; r < ROWS; r += 8) {
        int i = row0 + r;
        float acc = yb[i * TT + t];
        float ynext = (t < 31) ? yb[i * TT + t + 1] : 0.0f;
        const uint4* rwp = (const uint4*)&bm[r * WPR];
        for (int w4 = 0; w4 < WPR / 4; ++w4) {
            uint4 bw = rwp[w4];
            int jb = w4 * 128;
            unsigned int w;
            w = bw.x; while (w) { int j = __ffs(w) - 1; w &= w - 1; acc += yb[(jb +      j) * TT + t]; }
            w = bw.y; while (w) { int j = __ffs(w) - 1; w &= w - 1; acc += yb[(jb + 32 + j) * TT + t]; }
            w = bw.z; while (w) { int j = __ffs(w) - 1; w &= w - 1; acc += yb[(jb + 64 + j) * TT + t]; }
            w = bw.w; while (w) { int j = __ffs(w) - 1; w &= w - 1; acc += yb[(jb + 96 + j) * TT + t]; }
        }
        if (t < 31) total += fmaxf(ynext - acc, 0.0f);
    }
    #pragma unroll
    for (int off = 32; off; off >>= 1) total += __shfl_down(total, off, 64);
    if ((tid & 63) == 0) atomicAdd(out, total);
}

extern "C" void kernel_launch(void* const* d_in, const int* in_sizes, int n_in,
                              void* d_out, int out_size, void* d_ws, size_t ws_size,
                              hipStream_t stream) {
    const float* y = (const float*)d_in[0];     // (BS*M, TT) f32
    const int* coo = (const int*)d_in[1];       // (BS, 2, EE) delivered as int32
    float* out = (float*)d_out;

    if (ws_size >= WS_NEED) {
        // slots at the END of ws (last-poisoned -> L2-warm); partials just below.
        size_t slot_off = (ws_size - SLOT_BYTES) & ~(size_t)255;
        size_t part_off = (slot_off - PART_BYTES) & ~(size_t)255;
        unsigned int* slots = (unsigned int*)((char*)d_ws + slot_off);
        float* partials = (float*)((char*)d_ws + part_off);
        // no memset: poison/garbage are valid "empty" sentinels (range check)
        build_slots<<<(BS * EE) / 256, 256, 0, stream>>>(coo, slots);
        compute_slots<<<NBLK, 256, 0, stream>>>(y, slots, partials);
        reduce_partials<<<1, 1024, 0, stream>>>(partials, out);
    } else {
        hipMemsetAsync(out, 0, sizeof(float), stream);
        nil_reg_lds<<<BS * NCHUNK, 256, 0, stream>>>(y, coo, out);
    }
}

// Round 15
// 109.567 us; speedup vs baseline: 1.2032x; 1.2032x over previous
//
#include <hip/hip_runtime.h>

// Problem constants (fixed by setup_inputs): bs=8, m=4096, T=32, E=65536
#define M      4096
#define TT     32
#define BS     8
#define EE     65536
#define NROWS  (BS * M)                   // 32768
#define SLOTS  64                         // hash slots per row (load ~27%)
#define NBLK   (NROWS / 16)               // compute grid = 2048 blocks (2 rows/group)

// ws layout: [slots 8 MB][partials 8 KB]
// The 8 MB memset is mandatory: it warms the coherence point for the CAS
// atomics (R12: removing it cost +25us; R14: end-of-ws placement instead of
// memset cost +23us). Do not remove.
#define SLOT_BYTES ((size_t)NROWS * SLOTS * 4)
#define PART_BYTES ((size_t)NBLK * 4)
#define WS_NEED    (SLOT_BYTES + PART_BYTES)

// ---------------- Fast path ----------------

// One edge per thread (max TLP). Open-addressed per-row hash with atomicCAS:
// sentinel 0, value tgt+1, linear probe from tgt&63. Dedup happens here for
// free (CAS sees existing equal value -> no-op).
__global__ __launch_bounds__(256) void build_slots(const int* __restrict__ coo,
                                                   unsigned int* __restrict__ slots) {
    int idx = blockIdx.x * 256 + threadIdx.x;     // [0, BS*EE)
    int b = idx >> 16;
    int e = idx & (EE - 1);
    const int* base = coo + (size_t)b * 2 * EE;
    int src = base[e] & (M - 1);
    int tgt = base[EE + e] & (M - 1);
    unsigned int* row = slots + ((size_t)(b * M + src) << 6);
    unsigned int val = (unsigned int)tgt + 1u;    // in [1, 4096]
    int s = tgt & (SLOTS - 1);
    #pragma unroll 1
    for (int probe = 0; probe < SLOTS; ++probe) { // bounded; table load ~27%
        unsigned int old = atomicCAS(&row[s], 0u, val);
        if (old == 0u || old == val) break;       // claimed, or dup -> done
        s = (s + 1) & (SLOTS - 1);
    }
}

// One 32-lane group per TWO adjacent rows (lane = t = column). Slot loads
// coalesce (512 B/group). Ballot-compacted gather: iterate only the ~16
// occupied slots per row instead of all 64 (4x fewer gather loads). The
// ffs/mask chain is register-only; gathers stay independent.
__global__ __launch_bounds__(256) void compute_slots(const float* __restrict__ y,
                                                     const unsigned int* __restrict__ slots,
                                                     float* __restrict__ partials) {
    __shared__ float wsum[4];
    const int tid = threadIdx.x;
    const int t = tid & 31;                        // column t
    const int grp = tid >> 5;                      // 8 groups/block
    const int half = grp & 1;                      // position within the wave
    const int rowA = blockIdx.x * 16 + grp * 2;    // two adjacent rows
    const int b = rowA >> 12;                      // same batch (16-aligned)
    const int iA = rowA & (M - 1);
    const int iB = iA + 1;

    const float* yb = y + (size_t)b * M * TT;
    const unsigned int* rs = slots + ((size_t)rowA << 6);
    unsigned int a0 = rs[t];                       // 512 B contiguous per group
    unsigned int a1 = rs[t + 32];
    unsigned int b0 = rs[t + 64];
    unsigned int b1 = rs[t + 96];

    // Group-uniform occupancy masks (slot != 0 after memset+build).
    unsigned int mA0 = (unsigned int)(__ballot(a0 != 0u) >> (half ? 32 : 0));
    unsigned int mA1 = (unsigned int)(__ballot(a1 != 0u) >> (half ? 32 : 0));
    unsigned int mB0 = (unsigned int)(__ballot(b0 != 0u) >> (half ? 32 : 0));
    unsigned int mB1 = (unsigned int)(__ballot(b1 != 0u) >> (half ? 32 : 0));

    float accA = yb[iA * TT + t];                  // identity (eye) terms
    float accB = yb[iB * TT + t];
    float ynA = (t < 31) ? yb[iA * TT + t + 1] : 0.0f;
    float ynB = (t < 31) ? yb[iB * TT + t + 1] : 0.0f;

    while (mA0) { int k = __ffs(mA0) - 1; mA0 &= mA0 - 1;
        int j = (int)__shfl(a0, k, 32) - 1; accA += yb[j * TT + t]; }
    while (mA1) { int k = __ffs(mA1) - 1; mA1 &= mA1 - 1;
        int j = (int)__shfl(a1, k, 32) - 1; accA += yb[j * TT + t]; }
    while (mB0) { int k = __ffs(mB0) - 1; mB0 &= mB0 - 1;
        int j = (int)__shfl(b0, k, 32) - 1; accB += yb[j * TT + t]; }
    while (mB1) { int k = __ffs(mB1) - 1; mB1 &= mB1 - 1;
        int j = (int)__shfl(b1, k, 32) - 1; accB += yb[j * TT + t]; }

    float v = 0.0f;
    if (t < 31) v = fmaxf(ynA - accA, 0.0f) + fmaxf(ynB - accB, 0.0f);
    #pragma unroll
    for (int off = 32; off; off >>= 1) v += __shfl_down(v, off, 64);

    if ((tid & 63) == 0) wsum[tid >> 6] = v;
    __syncthreads();
    if (tid == 0) partials[blockIdx.x] = wsum[0] + wsum[1] + wsum[2] + wsum[3];
}

// Single block sums the 2048 partials. No atomics anywhere.
__global__ __launch_bounds__(1024) void reduce_partials(const float* __restrict__ p,
                                                        float* __restrict__ out) {
    const int tid = threadIdx.x;
    float s = 0.0f;
    for (int k = tid; k < NBLK; k += 1024) s += p[k];
    #pragma unroll
    for (int off = 32; off; off >>= 1) s += __shfl_down(s, off, 64);
    __shared__ float ws[16];
    if ((tid & 63) == 0) ws[tid >> 6] = s;
    __syncthreads();
    if (tid == 0) {
        float tot = 0.0f;
        #pragma unroll
        for (int k = 0; k < 16; ++k) tot += ws[k];
        out[0] = tot;
    }
}

// ---------------- Fallback (R3): LDS bitmap, no scratch ----------------
#define WPR    128
#define ROWS   64
#define NCHUNK (M / ROWS)

__global__ __launch_bounds__(256) void nil_reg_lds(const float* __restrict__ y,
                                                   const int* __restrict__ coo,
                                                   float* __restrict__ out) {
    __shared__ unsigned int bm[ROWS * WPR];
    const int tid = threadIdx.x;
    const int b = blockIdx.x / NCHUNK;
    const int chunk = blockIdx.x % NCHUNK;
    const int row0 = chunk * ROWS;
    for (int i = tid; i < ROWS * WPR; i += 256) bm[i] = 0;
    __syncthreads();
    const int* base = coo + (size_t)b * 2 * EE;
    for (int e = tid; e < EE; e += 256) {
        int src = base[e] & (M - 1);
        int tgt = base[EE + e] & (M - 1);
        int r = src - row0;
        if ((unsigned)r < (unsigned)ROWS)
            atomicOr(&bm[r * WPR + (tgt >> 5)], 1u << (tgt & 31));
    }
    __syncthreads();
    const float* yb = y + (size_t)b * M * TT;
    const int t = tid & 31;
    const int grp = tid >> 5;
    float total = 0.0f;
    for (int r = grp; r < ROWS; r += 8) {
        int i = row0 + r;
        float acc = yb[i * TT + t];
        float ynext = (t < 31) ? yb[i * TT + t + 1] : 0.0f;
        const uint4* rwp = (const uint4*)&bm[r * WPR];
        for (int w4 = 0; w4 < WPR / 4; ++w4) {
            uint4 bw = rwp[w4];
            int jb = w4 * 128;
            unsigned int w;
            w = bw.x; while (w) { int j = __ffs(w) - 1; w &= w - 1; acc += yb[(jb +      j) * TT + t]; }
            w = bw.y; while (w) { int j = __ffs(w) - 1; w &= w - 1; acc += yb[(jb + 32 + j) * TT + t]; }
            w = bw.z; while (w) { int j = __ffs(w) - 1; w &= w - 1; acc += yb[(jb + 64 + j) * TT + t]; }
            w = bw.w; while (w) { int j = __ffs(w) - 1; w &= w - 1; acc += yb[(jb + 96 + j) * TT + t]; }
        }
        if (t < 31) total += fmaxf(ynext - acc, 0.0f);
    }
    #pragma unroll
    for (int off = 32; off; off >>= 1) total += __shfl_down(total, off, 64);
    if ((tid & 63) == 0) atomicAdd(out, total);
}

extern "C" void kernel_launch(void* const* d_in, const int* in_sizes, int n_in,
                              void* d_out, int out_size, void* d_ws, size_t ws_size,
                              hipStream_t stream) {
    const float* y = (const float*)d_in[0];     // (BS*M, TT) f32
    const int* coo = (const int*)d_in[1];       // (BS, 2, EE) delivered as int32
    float* out = (float*)d_out;

    if (ws_size >= WS_NEED) {
        char* ws = (char*)d_ws;
        unsigned int* slots = (unsigned int*)ws;
        float* partials = (float*)(ws + SLOT_BYTES);
        hipMemsetAsync(slots, 0, SLOT_BYTES, stream);   // sentinel init + atomic warm
        build_slots<<<(BS * EE) / 256, 256, 0, stream>>>(coo, slots);
        compute_slots<<<NBLK, 256, 0, stream>>>(y, slots, partials);
        reduce_partials<<<1, 1024, 0, stream>>>(partials, out);
    } else {
        hipMemsetAsync(out, 0, sizeof(float), stream);
        nil_reg_lds<<<BS * NCHUNK, 256, 0, stream>>>(y, coo, out);
    }
}